// Round 19
// baseline (114.255 us; speedup 1.0000x reference)
//
#include <hip/hip_runtime.h>
#include <stdint.h>

#define BI 128
#define BT 128
#define RR 36
#define WW 50
#define DD 1024
#define NN 6400       /* fg row stride, static */
#define SEPS 1e-6f
#define L2E20 28.853900817779268f   /* 20/ln2 */

typedef __attribute__((ext_vector_type(8))) short short8v;
typedef __attribute__((ext_vector_type(4))) float float4v;
typedef __attribute__((ext_vector_type(2))) unsigned int uint2v;

__device__ __forceinline__ unsigned short f2bf(float f){
  unsigned u = __float_as_uint(f);
  return (unsigned short)((u + 0x7FFFu + ((u >> 16) & 1u)) >> 16);
}

// ---- integer wave-wide sum (lane movement validated R8-R18) ----
template<int CTRL>
__device__ __forceinline__ int dpp_addi(int x){
  int y = __builtin_amdgcn_mov_dpp(x, CTRL, 0xF, 0xF, true);
  return x + y;
}
__device__ __forceinline__ int iwaveSum(int x){
  x = dpp_addi<0x121>(x);
  x = dpp_addi<0x122>(x);
  x = dpp_addi<0x124>(x);
  x = dpp_addi<0x128>(x);
  {
    uint2v r = __builtin_amdgcn_permlane16_swap((unsigned)x, (unsigned)x, false, false);
    x = (int)r[0] + (int)r[1];
  }
  {
    uint2v r = __builtin_amdgcn_permlane32_swap((unsigned)x, (unsigned)x, false, false);
    x = (int)r[0] + (int)r[1];
  }
  return x;
}
__device__ __forceinline__ int maskedSum128(const int* __restrict__ v,
                                            int lim, int lane){
  const int a = v[2 * lane];
  const int b = v[2 * lane + 1];
  int s = ((2 * lane) < lim ? a : 0) + ((2 * lane + 1) < lim ? b : 0);
  return iwaveSum(s);
}

// ---- gather valid rows + f32->bf16 convert; persists rowoff/coloff (R18) ----
__global__ __launch_bounds__(256) void gather_cvt_kernel(
    const float* __restrict__ imgs, const float* __restrict__ caps,
    const int* __restrict__ il, const int* __restrict__ cl,
    unsigned short* __restrict__ Ab, unsigned short* __restrict__ Bb,
    int* __restrict__ rowoff, int* __restrict__ coloff){
  const int b = blockIdx.x;
  const int t = threadIdx.x;
  const int lane = t & 63;
  if (b < BI * RR){
    const int i = b / RR, r = b % RR;
    if (r >= il[i]) return;
    const int ro = maskedSum128(il, i, lane);
    if (r == 0 && t == 0) rowoff[i] = ro;
    const float4 v = *(const float4*)(imgs + (size_t)b * DD + t * 4);
    ushort4 o = make_ushort4(f2bf(v.x), f2bf(v.y), f2bf(v.z), f2bf(v.w));
    *(ushort4*)(Ab + (size_t)(ro + r) * DD + t * 4) = o;
  } else {
    const int bb = b - BI * RR;
    const int c = bb / WW, w = bb % WW;
    if (w >= cl[c]) return;
    const int co = maskedSum128(cl, c, lane);
    if (w == 0 && t == 0) coloff[c] = co;
    const float4 v = *(const float4*)(caps + (size_t)bb * DD + t * 4);
    ushort4 o = make_ushort4(f2bf(v.x), f2bf(v.y), f2bf(v.z), f2bf(v.w));
    *(ushort4*)(Bb + (size_t)(co + w) * DD + t * 4) = o;
  }
}

// ---- R19 primary: K-SPLIT GEMM. bx = (tile<<1)|kh; kh computes chunks
// [16kh, 16kh+16) into C0/C1. Same tiles, same total staged traffic, 2x
// active blocks (1288) -> TLP up, block tail halves. Pipeline = R10/R11's
// validated triple-buffer depth-2 (chunk rel n -> buf n%3, vmcnt(8)). ----
__global__ __launch_bounds__(256) void gemm16_kernel(
    const unsigned short* __restrict__ A, const unsigned short* __restrict__ B,
    const int* __restrict__ il, const int* __restrict__ cl,
    float* __restrict__ C0, float* __restrict__ C1){
  __shared__ __align__(16) unsigned char LDS[49152];
  const int tid = threadIdx.x;
  const int lane = tid & 63, wv = tid >> 6;
  const int Mp = __builtin_amdgcn_readfirstlane(maskedSum128(il, BI, lane));
  const int Np = __builtin_amdgcn_readfirstlane(maskedSum128(cl, BT, lane));
  const int nnb = (Np + 127) >> 7;
  const int nact = ((Mp + 127) >> 7) * nnb;
  const int bx = blockIdx.x;
  const int tile = bx >> 1;
  if (tile >= nact) return;
  const int kh = bx & 1;
  const int k0 = kh << 4;                         // chunk base (16 chunks)
  float* __restrict__ C = kh ? C1 : C0;
  const int mb = tile / nnb, nb = tile - mb * nnb;
  const int m0 = mb * 128, n0 = nb * 128;

  const int l15 = lane & 15, lhi = lane >> 4;
  const int wr = wv >> 1, wc = wv & 1;

  const unsigned short* sp[4];
  #pragma unroll
  for (int j = 0; j < 4; j++){
    const int u = j * 256 + tid;
    const int v = u & 511;
    const int sup = v >> 3, slot = v & 7;
    const int sub = slot ^ (sup & 7);             // inverse of store swizzle
    const int row = sup * 2 + (sub >> 2);
    const int kg  = sub & 3;
    sp[j] = ((u < 512) ? (A + (size_t)(m0 + row) * DD)
                       : (B + (size_t)(n0 + row) * DD)) + kg * 8;
  }

  float4v acc[4][4];
  #pragma unroll
  for (int a1 = 0; a1 < 4; a1++)
    #pragma unroll
    for (int b1 = 0; b1 < 4; b1++)
      acc[a1][b1] = (float4v){0.f, 0.f, 0.f, 0.f};

#define STAGE(BUF, CH) { \
    _Pragma("unroll") \
    for (int j = 0; j < 4; j++) \
      __builtin_amdgcn_global_load_lds( \
          (const __attribute__((address_space(1))) void*)(sp[j] + (CH) * 32), \
          (__attribute__((address_space(3))) void*)(LDS + (BUF) * 16384 + (j * 256 + tid) * 16), \
          16, 0, 0); }
#define LUNIT(row) (((row) >> 1) * 8 + (((((row) & 1) << 2) + lhi) ^ (((row) >> 1) & 7)))
#define COMPUTE(BUF) { \
    short8v af[4], bf[4]; \
    _Pragma("unroll") \
    for (int tr = 0; tr < 4; tr++){ \
      const int row = wr * 64 + tr * 16 + l15; \
      af[tr] = *(const short8v*)(LDS + (BUF) * 16384 + LUNIT(row) * 16); \
    } \
    _Pragma("unroll") \
    for (int tw = 0; tw < 4; tw++){ \
      const int row = wc * 64 + tw * 16 + l15; \
      bf[tw] = *(const short8v*)(LDS + (BUF) * 16384 + 8192 + LUNIT(row) * 16); \
    } \
    _Pragma("unroll") \
    for (int tr = 0; tr < 4; tr++) \
      _Pragma("unroll") \
      for (int tw = 0; tw < 4; tw++) \
        acc[tr][tw] = __builtin_amdgcn_mfma_f32_16x16x32_bf16( \
            af[tr], bf[tw], acc[tr][tw], 0, 0, 0); }
#define WAIT8  asm volatile("s_waitcnt vmcnt(8)" ::: "memory")
#define WAIT4  asm volatile("s_waitcnt vmcnt(4)" ::: "memory")
#define WAIT0  asm volatile("s_waitcnt vmcnt(0)" ::: "memory")
#define BAR    __builtin_amdgcn_s_barrier()

  STAGE(0, k0 + 0);
  STAGE(1, k0 + 1);
  #pragma unroll 1
  for (int k = 0; k < 4; k++){    // rel chunks 3k..3k+2
    const int c = k0 + 3 * k;
    STAGE(2, c + 2); WAIT8; BAR; COMPUTE(0); BAR;
    STAGE(0, c + 3); WAIT8; BAR; COMPUTE(1); BAR;
    STAGE(1, c + 4); WAIT8; BAR; COMPUTE(2); BAR;
  }
  // computed rel 0..11, staged rel..13 (12->buf0, 13->buf1)
  STAGE(2, k0 + 14); WAIT8; BAR; COMPUTE(0); BAR;   // rel 12
  STAGE(0, k0 + 15); WAIT8; BAR; COMPUTE(1); BAR;   // rel 13
  WAIT4; BAR; COMPUTE(2); BAR;                      // rel 14
  WAIT0; BAR; COMPUTE(0);                           // rel 15

#undef STAGE
#undef LUNIT
#undef COMPUTE
#undef WAIT8
#undef WAIT4
#undef WAIT0
#undef BAR

  #pragma unroll
  for (int tr = 0; tr < 4; tr++)
    #pragma unroll
    for (int tw = 0; tw < 4; tw++)
      #pragma unroll
      for (int j = 0; j < 4; j++){
        int m = m0 + wr * 64 + tr * 16 + lhi * 4 + j;
        int n = n0 + wc * 64 + tw * 16 + l15;
        C[(size_t)m * NN + n] = acc[tr][tw][j];
      }
}

// ---- fallback: full-K GEMM (exact R18 body) for small ws ----
__global__ __launch_bounds__(256) void gemm32_kernel(
    const unsigned short* __restrict__ A, const unsigned short* __restrict__ B,
    const int* __restrict__ il, const int* __restrict__ cl,
    float* __restrict__ C){
  __shared__ __align__(16) unsigned char LDS[49152];
  const int tid = threadIdx.x;
  const int lane = tid & 63, wv = tid >> 6;
  const int Mp = __builtin_amdgcn_readfirstlane(maskedSum128(il, BI, lane));
  const int Np = __builtin_amdgcn_readfirstlane(maskedSum128(cl, BT, lane));
  const int nnb = (Np + 127) >> 7;
  const int nact = ((Mp + 127) >> 7) * nnb;
  const int bx = blockIdx.x;
  if (bx >= nact) return;
  const int mb = bx / nnb, nb = bx - mb * nnb;
  const int m0 = mb * 128, n0 = nb * 128;
  const int l15 = lane & 15, lhi = lane >> 4;
  const int wr = wv >> 1, wc = wv & 1;

  const unsigned short* sp[4];
  #pragma unroll
  for (int j = 0; j < 4; j++){
    const int u = j * 256 + tid;
    const int v = u & 511;
    const int sup = v >> 3, slot = v & 7;
    const int sub = slot ^ (sup & 7);
    const int row = sup * 2 + (sub >> 2);
    const int kg  = sub & 3;
    sp[j] = ((u < 512) ? (A + (size_t)(m0 + row) * DD)
                       : (B + (size_t)(n0 + row) * DD)) + kg * 8;
  }

  float4v acc[4][4];
  #pragma unroll
  for (int a1 = 0; a1 < 4; a1++)
    #pragma unroll
    for (int b1 = 0; b1 < 4; b1++)
      acc[a1][b1] = (float4v){0.f, 0.f, 0.f, 0.f};

#define STAGE(BUF, CH) { \
    _Pragma("unroll") \
    for (int j = 0; j < 4; j++) \
      __builtin_amdgcn_global_load_lds( \
          (const __attribute__((address_space(1))) void*)(sp[j] + (CH) * 32), \
          (__attribute__((address_space(3))) void*)(LDS + (BUF) * 16384 + (j * 256 + tid) * 16), \
          16, 0, 0); }
#define LUNIT(row) (((row) >> 1) * 8 + (((((row) & 1) << 2) + lhi) ^ (((row) >> 1) & 7)))
#define COMPUTE(BUF) { \
    short8v af[4], bf[4]; \
    _Pragma("unroll") \
    for (int tr = 0; tr < 4; tr++){ \
      const int row = wr * 64 + tr * 16 + l15; \
      af[tr] = *(const short8v*)(LDS + (BUF) * 16384 + LUNIT(row) * 16); \
    } \
    _Pragma("unroll") \
    for (int tw = 0; tw < 4; tw++){ \
      const int row = wc * 64 + tw * 16 + l15; \
      bf[tw] = *(const short8v*)(LDS + (BUF) * 16384 + 8192 + LUNIT(row) * 16); \
    } \
    _Pragma("unroll") \
    for (int tr = 0; tr < 4; tr++) \
      _Pragma("unroll") \
      for (int tw = 0; tw < 4; tw++) \
        acc[tr][tw] = __builtin_amdgcn_mfma_f32_16x16x32_bf16( \
            af[tr], bf[tw], acc[tr][tw], 0, 0, 0); }
#define WAIT8  asm volatile("s_waitcnt vmcnt(8)" ::: "memory")
#define WAIT4  asm volatile("s_waitcnt vmcnt(4)" ::: "memory")
#define WAIT0  asm volatile("s_waitcnt vmcnt(0)" ::: "memory")
#define BAR    __builtin_amdgcn_s_barrier()

  STAGE(0, 0);
  STAGE(1, 1);
  #pragma unroll 1
  for (int k = 0; k < 10; k++){
    const int c = 3 * k;
    STAGE(2, c + 2); WAIT8; BAR; COMPUTE(0); BAR;
    STAGE(0, c + 3); WAIT8; BAR; COMPUTE(1); BAR;
    STAGE(1, c + 4); WAIT8; BAR; COMPUTE(2); BAR;
  }
  WAIT4; BAR; COMPUTE(0); BAR;
  WAIT0; BAR; COMPUTE(1);

#undef STAGE
#undef LUNIT
#undef COMPUTE
#undef WAIT8
#undef WAIT4
#undef WAIT0
#undef BAR

  #pragma unroll
  for (int tr = 0; tr < 4; tr++)
    #pragma unroll
    for (int tw = 0; tw < 4; tw++)
      #pragma unroll
      for (int j = 0; j < 4; j++){
        int m = m0 + wr * 64 + tr * 16 + lhi * 4 + j;
        int n = n0 + wc * 64 + tw * 16 + l15;
        C[(size_t)m * NN + n] = acc[tr][tw][j];
      }
}

// ---- float reduction helpers (validated R1-R18) ----
template<int CTRL>
__device__ __forceinline__ float dpp_add(float x){
  int y = __builtin_amdgcn_mov_dpp(__float_as_int(x), CTRL, 0xF, 0xF, true);
  return x + __int_as_float(y);
}
__device__ __forceinline__ float q16sum(float x){
  x = dpp_add<0x121>(x);
  x = dpp_add<0x122>(x);
  x = dpp_add<0x124>(x);
  x = dpp_add<0x128>(x);
  return x;
}
__device__ __forceinline__ float pl16comb(float x){
  unsigned xi = __float_as_uint(x);
  uint2v r = __builtin_amdgcn_permlane16_swap(xi, xi, false, false);
  return __uint_as_float(r[0]) + __uint_as_float(r[1]);
}
__device__ __forceinline__ float pl32comb(float x){
  unsigned xi = __float_as_uint(x);
  uint2v r = __builtin_amdgcn_permlane32_swap(xi, xi, false, false);
  return __uint_as_float(r[0]) + __uint_as_float(r[1]);
}

// ---- Sinkhorn (R11/R18 body) over fg = fg1 + fg2 (K-split partials).
// Straight-line; extra loads folded to keep live set near R18's 64 VGPR. ----
__global__ __launch_bounds__(256) void sink_split_kernel(
    const float* __restrict__ fg, const float* __restrict__ fgb,
    const int* __restrict__ il, const int* __restrict__ cl,
    const int* __restrict__ rowoff, const int* __restrict__ coloff,
    float* __restrict__ out){
  const int lane = threadIdx.x & 63;
  const int gw = blockIdx.x * 4 + (threadIdx.x >> 6);
  const int i = gw >> 7, c = gw & 127;
  const int q = lane >> 4, t = lane & 15;

  const int ilen = __builtin_amdgcn_readfirstlane(il[i]);
  const int clen = __builtin_amdgcn_readfirstlane(cl[c]);
  const int ro   = __builtin_amdgcn_readfirstlane(rowoff[i]);
  const int co   = __builtin_amdgcn_readfirstlane(coloff[c]);
  const float* base  = fg  + (size_t)ro * NN + co;
  const float* base2 = fgb + (size_t)ro * NN + co;
  const float inv_il = __fdividef(1.0f, (float)ilen);
  const float inv_cl = __fdividef(1.0f, (float)clen);
  const bool v0 = (t      < clen);
  const bool v1 = (t + 16 < clen);
  const bool v2 = (t + 32 < clen);
  const bool v3 = (t + 48 < clen);
  const int r0 = 9 * q;
  const int off0 = r0 * NN + t;

  float p0[9], p1[9], p2[9], p3[9];
  float ts = 0.f;
  #pragma unroll
  for (int k = 0; k < 9; k++){
    const bool rv = (r0 + k) < ilen;
    const int x = off0 + k * NN;
    const float a0 = base[x]      + base2[x];
    const float a1 = base[x + 16] + base2[x + 16];
    const float a2 = base[x + 32] + base2[x + 32];
    const float a3 = base[x + 48] + base2[x + 48];
    p0[k] = (rv && v0) ? exp2f(fmaf(a0, L2E20, -L2E20)) : 0.f;
    p1[k] = (rv && v1) ? exp2f(fmaf(a1, L2E20, -L2E20)) : 0.f;
    p2[k] = (rv && v2) ? exp2f(fmaf(a2, L2E20, -L2E20)) : 0.f;
    p3[k] = (rv && v3) ? exp2f(fmaf(a3, L2E20, -L2E20)) : 0.f;
    ts += (p0[k] + p1[k]) + (p2[k] + p3[k]);
  }
  ts = q16sum(ts);
  ts = pl16comb(ts);
  ts = pl32comb(ts);
  const float sc = __fdividef(1.0f, ts + SEPS);
  #pragma unroll
  for (int k = 0; k < 9; k++){
    p0[k] *= sc; p1[k] *= sc; p2[k] *= sc; p3[k] *= sc;
  }

  for (int it = 0; it < 3; it++){
    #pragma unroll
    for (int k = 0; k < 9; k++){
      float u = (p0[k] + p1[k]) + (p2[k] + p3[k]);
      u = q16sum(u);
      const float rs = __fdividef(inv_il, u + SEPS);
      p0[k] *= rs; p1[k] *= rs; p2[k] *= rs; p3[k] *= rs;
    }
    float s0 = 0.f, s1 = 0.f, s2 = 0.f, s3 = 0.f;
    #pragma unroll
    for (int k = 0; k < 9; k++){
      s0 += p0[k]; s1 += p1[k]; s2 += p2[k]; s3 += p3[k];
    }
    s0 = pl16comb(s0); s0 = pl32comb(s0);
    s1 = pl16comb(s1); s1 = pl32comb(s1);
    s2 = pl16comb(s2); s2 = pl32comb(s2);
    s3 = pl16comb(s3); s3 = pl32comb(s3);
    const float cs0 = __fdividef(inv_cl, s0 + SEPS);
    const float cs1 = __fdividef(inv_cl, s1 + SEPS);
    const float cs2 = __fdividef(inv_cl, s2 + SEPS);
    const float cs3 = __fdividef(inv_cl, s3 + SEPS);
    #pragma unroll
    for (int k = 0; k < 9; k++){
      p0[k] *= cs0; p1[k] *= cs1; p2[k] *= cs2; p3[k] *= cs3;
    }
  }

  float sim = 0.f;
  #pragma unroll
  for (int k = 0; k < 9; k++){           // f = b1+b2 via two fmas (no add)
    const int x = off0 + k * NN;
    sim = fmaf(base[x],       p0[k], sim); sim = fmaf(base2[x],      p0[k], sim);
    sim = fmaf(base[x + 16],  p1[k], sim); sim = fmaf(base2[x + 16], p1[k], sim);
    sim = fmaf(base[x + 32],  p2[k], sim); sim = fmaf(base2[x + 32], p2[k], sim);
    sim = fmaf(base[x + 48],  p3[k], sim); sim = fmaf(base2[x + 48], p3[k], sim);
  }
  sim = q16sum(sim);
  sim = pl16comb(sim);
  sim = pl32comb(sim);
  if (lane == 0) out[i * BT + c] = sim;
}

// ---- fallback sink: exact R18 body ----
__global__ __launch_bounds__(256) void sink_kernel(
    const float* __restrict__ fg, const int* __restrict__ il,
    const int* __restrict__ cl, const int* __restrict__ rowoff,
    const int* __restrict__ coloff, float* __restrict__ out){
  const int lane = threadIdx.x & 63;
  const int gw = blockIdx.x * 4 + (threadIdx.x >> 6);
  const int i = gw >> 7, c = gw & 127;
  const int q = lane >> 4, t = lane & 15;

  const int ilen = __builtin_amdgcn_readfirstlane(il[i]);
  const int clen = __builtin_amdgcn_readfirstlane(cl[c]);
  const int ro   = __builtin_amdgcn_readfirstlane(rowoff[i]);
  const int co   = __builtin_amdgcn_readfirstlane(coloff[c]);
  const float* base = fg + (size_t)ro * NN + co;
  const float inv_il = __fdividef(1.0f, (float)ilen);
  const float inv_cl = __fdividef(1.0f, (float)clen);
  const bool v0 = (t      < clen);
  const bool v1 = (t + 16 < clen);
  const bool v2 = (t + 32 < clen);
  const bool v3 = (t + 48 < clen);
  const int r0 = 9 * q;
  const int off0 = r0 * NN + t;

  float p0[9], p1[9], p2[9], p3[9];
  float ts = 0.f;
  #pragma unroll
  for (int k = 0; k < 9; k++){
    const bool rv = (r0 + k) < ilen;
    const float a0 = base[off0 + k * NN];
    const float a1 = base[off0 + k * NN + 16];
    const float a2 = base[off0 + k * NN + 32];
    const float a3 = base[off0 + k * NN + 48];
    p0[k] = (rv && v0) ? exp2f(fmaf(a0, L2E20, -L2E20)) : 0.f;
    p1[k] = (rv && v1) ? exp2f(fmaf(a1, L2E20, -L2E20)) : 0.f;
    p2[k] = (rv && v2) ? exp2f(fmaf(a2, L2E20, -L2E20)) : 0.f;
    p3[k] = (rv && v3) ? exp2f(fmaf(a3, L2E20, -L2E20)) : 0.f;
    ts += (p0[k] + p1[k]) + (p2[k] + p3[k]);
  }
  ts = q16sum(ts);
  ts = pl16comb(ts);
  ts = pl32comb(ts);
  const float sc = __fdividef(1.0f, ts + SEPS);
  #pragma unroll
  for (int k = 0; k < 9; k++){
    p0[k] *= sc; p1[k] *= sc; p2[k] *= sc; p3[k] *= sc;
  }
  for (int it = 0; it < 3; it++){
    #pragma unroll
    for (int k = 0; k < 9; k++){
      float u = (p0[k] + p1[k]) + (p2[k] + p3[k]);
      u = q16sum(u);
      const float rs = __fdividef(inv_il, u + SEPS);
      p0[k] *= rs; p1[k] *= rs; p2[k] *= rs; p3[k] *= rs;
    }
    float s0 = 0.f, s1 = 0.f, s2 = 0.f, s3 = 0.f;
    #pragma unroll
    for (int k = 0; k < 9; k++){
      s0 += p0[k]; s1 += p1[k]; s2 += p2[k]; s3 += p3[k];
    }
    s0 = pl16comb(s0); s0 = pl32comb(s0);
    s1 = pl16comb(s1); s1 = pl32comb(s1);
    s2 = pl16comb(s2); s2 = pl32comb(s2);
    s3 = pl16comb(s3); s3 = pl32comb(s3);
    const float cs0 = __fdividef(inv_cl, s0 + SEPS);
    const float cs1 = __fdividef(inv_cl, s1 + SEPS);
    const float cs2 = __fdividef(inv_cl, s2 + SEPS);
    const float cs3 = __fdividef(inv_cl, s3 + SEPS);
    #pragma unroll
    for (int k = 0; k < 9; k++){
      p0[k] *= cs0; p1[k] *= cs1; p2[k] *= cs2; p3[k] *= cs3;
    }
  }
  float sim = 0.f;
  #pragma unroll
  for (int k = 0; k < 9; k++){
    sim = fmaf(base[off0 + k * NN],      p0[k], sim);
    sim = fmaf(base[off0 + k * NN + 16], p1[k], sim);
    sim = fmaf(base[off0 + k * NN + 32], p2[k], sim);
    sim = fmaf(base[off0 + k * NN + 48], p3[k], sim);
  }
  sim = q16sum(sim);
  sim = pl16comb(sim);
  sim = pl32comb(sim);
  if (lane == 0) out[i * BT + c] = sim;
}

extern "C" void kernel_launch(void* const* d_in, const int* in_sizes, int n_in,
                              void* d_out, int out_size, void* d_ws, size_t ws_size,
                              hipStream_t stream){
  const float* imgs = (const float*)d_in[0];
  const float* caps = (const float*)d_in[1];
  const int* il = (const int*)d_in[2];
  const int* cl = (const int*)d_in[3];
  float* out = (float*)d_out;

  // ws layout: [rowoff 128][coloff 128][pad to 1KB] Ab, Bb, fg, (fg2)
  int* rowoff = (int*)d_ws;
  int* coloff = rowoff + 128;
  unsigned short* Ab = (unsigned short*)((char*)d_ws + 1024);
  unsigned short* Bb = Ab + (size_t)BI * RR * DD;
  float* fg  = (float*)(Bb + (size_t)BT * WW * DD);
  float* fg2 = fg + (size_t)BI * RR * NN;

  const size_t fgBytes = (size_t)BI * RR * NN * 4;
  const size_t need2 = 1024 + ((size_t)BI * RR + (size_t)BT * WW) * DD * 2
                       + 2 * fgBytes;
  const bool split = (ws_size >= need2);   // ws_size fixed per session -> deterministic

  gather_cvt_kernel<<<BI * RR + BT * WW, 256, 0, stream>>>(
      imgs, caps, il, cl, Ab, Bb, rowoff, coloff);
  if (split){
    gemm16_kernel<<<2 * 36 * 50, 256, 0, stream>>>(Ab, Bb, il, cl, fg, fg2);
    sink_split_kernel<<<(BI * BT) / 4, 256, 0, stream>>>(
        fg, fg2, il, cl, rowoff, coloff, out);
  } else {
    gemm32_kernel<<<36 * 50, 256, 0, stream>>>(Ab, Bb, il, cl, fg);
    sink_kernel<<<(BI * BT) / 4, 256, 0, stream>>>(
        fg, il, cl, rowoff, coloff, out);
  }
}

// Round 20
// 96.651 us; speedup vs baseline: 1.1821x; 1.1821x over previous
//
#include <hip/hip_runtime.h>
#include <stdint.h>

#define BI 128
#define BT 128
#define RR 36
#define WW 50
#define DD 1024
#define NN 6400       /* fg row stride, static */
#define SEPS 1e-6f
#define L2E20 28.853900817779268f   /* 20/ln2 */

typedef __attribute__((ext_vector_type(8))) short short8v;
typedef __attribute__((ext_vector_type(4))) float float4v;
typedef __attribute__((ext_vector_type(2))) unsigned int uint2v;

__device__ __forceinline__ unsigned short f2bf(float f){
  unsigned u = __float_as_uint(f);
  return (unsigned short)((u + 0x7FFFu + ((u >> 16) & 1u)) >> 16);
}

// ---- integer wave-wide sum (lane movement validated R8-R18) ----
template<int CTRL>
__device__ __forceinline__ int dpp_addi(int x){
  int y = __builtin_amdgcn_mov_dpp(x, CTRL, 0xF, 0xF, true);
  return x + y;
}
__device__ __forceinline__ int iwaveSum(int x){
  x = dpp_addi<0x121>(x);
  x = dpp_addi<0x122>(x);
  x = dpp_addi<0x124>(x);
  x = dpp_addi<0x128>(x);
  {
    uint2v r = __builtin_amdgcn_permlane16_swap((unsigned)x, (unsigned)x, false, false);
    x = (int)r[0] + (int)r[1];
  }
  {
    uint2v r = __builtin_amdgcn_permlane32_swap((unsigned)x, (unsigned)x, false, false);
    x = (int)r[0] + (int)r[1];
  }
  return x;
}
// sum of v[j] for j < lim (v has 128 entries); every lane returns the total.
__device__ __forceinline__ int maskedSum128(const int* __restrict__ v,
                                            int lim, int lane){
  const int a = v[2 * lane];
  const int b = v[2 * lane + 1];
  int s = ((2 * lane) < lim ? a : 0) + ((2 * lane + 1) < lim ? b : 0);
  return iwaveSum(s);
}

// ---- gather valid rows + f32->bf16 convert. Block = one source row.
// (r==0)/(w==0) blocks also persist rowoff[i]/coloff[c] to ws so sink
// reads them as scalar loads (removes its 2 in-wave scans). ----
__global__ __launch_bounds__(256) void gather_cvt_kernel(
    const float* __restrict__ imgs, const float* __restrict__ caps,
    const int* __restrict__ il, const int* __restrict__ cl,
    unsigned short* __restrict__ Ab, unsigned short* __restrict__ Bb,
    int* __restrict__ rowoff, int* __restrict__ coloff){
  const int b = blockIdx.x;
  const int t = threadIdx.x;
  const int lane = t & 63;
  if (b < BI * RR){
    const int i = b / RR, r = b % RR;
    if (r >= il[i]) return;                       // block-uniform
    const int ro = maskedSum128(il, i, lane);     // rowoff[i], wave-computed
    if (r == 0 && t == 0) rowoff[i] = ro;         // persist for sink
    const float4 v = *(const float4*)(imgs + (size_t)b * DD + t * 4);
    ushort4 o = make_ushort4(f2bf(v.x), f2bf(v.y), f2bf(v.z), f2bf(v.w));
    *(ushort4*)(Ab + (size_t)(ro + r) * DD + t * 4) = o;
  } else {
    const int bb = b - BI * RR;
    const int c = bb / WW, w = bb % WW;
    if (w >= cl[c]) return;
    const int co = maskedSum128(cl, c, lane);     // coloff[c]
    if (w == 0 && t == 0) coloff[c] = co;
    const float4 v = *(const float4*)(caps + (size_t)bb * DD + t * 4);
    ushort4 o = make_ushort4(f2bf(v.x), f2bf(v.y), f2bf(v.z), f2bf(v.w));
    *(ushort4*)(Bb + (size_t)(co + w) * DD + t * 4) = o;
  }
}

// ---- 128x128 GEMM, BK=32, triple-buffered LDS, depth-2 prefetch, compact
// grid (validated R11-R18). Normal C stores (NT removed in R18: fg stays
// L3-resident for sink — isolated win). ----
__global__ __launch_bounds__(256) void gemm_kernel(
    const unsigned short* __restrict__ A, const unsigned short* __restrict__ B,
    const int* __restrict__ il, const int* __restrict__ cl,
    float* __restrict__ C){
  __shared__ __align__(16) unsigned char LDS[49152];
  const int tid = threadIdx.x;
  const int lane = tid & 63, wv = tid >> 6;
  const int Mp = __builtin_amdgcn_readfirstlane(maskedSum128(il, BI, lane));
  const int Np = __builtin_amdgcn_readfirstlane(maskedSum128(cl, BT, lane));
  const int nnb = (Np + 127) >> 7;
  const int nact = ((Mp + 127) >> 7) * nnb;
  const int bx = blockIdx.x;
  if (bx >= nact) return;                         // compact early-exit
  const int mb = bx / nnb, nb = bx - mb * nnb;
  const int m0 = mb * 128, n0 = nb * 128;

  const int l15 = lane & 15, lhi = lane >> 4;
  const int wr = wv >> 1, wc = wv & 1;            // 2x2 wave grid, 64x64/wave

  // staging sources: 4 units/thread/chunk (u = j*256+tid; A: u<512, B: u>=512)
  const unsigned short* sp[4];
  #pragma unroll
  for (int j = 0; j < 4; j++){
    const int u = j * 256 + tid;
    const int v = u & 511;
    const int sup = v >> 3, slot = v & 7;
    const int sub = slot ^ (sup & 7);             // inverse of store swizzle
    const int row = sup * 2 + (sub >> 2);
    const int kg  = sub & 3;
    sp[j] = ((u < 512) ? (A + (size_t)(m0 + row) * DD)
                       : (B + (size_t)(n0 + row) * DD)) + kg * 8;
  }

  float4v acc[4][4];
  #pragma unroll
  for (int a1 = 0; a1 < 4; a1++)
    #pragma unroll
    for (int b1 = 0; b1 < 4; b1++)
      acc[a1][b1] = (float4v){0.f, 0.f, 0.f, 0.f};

#define STAGE(BUF, CH) { \
    _Pragma("unroll") \
    for (int j = 0; j < 4; j++) \
      __builtin_amdgcn_global_load_lds( \
          (const __attribute__((address_space(1))) void*)(sp[j] + (CH) * 32), \
          (__attribute__((address_space(3))) void*)(LDS + (BUF) * 16384 + (j * 256 + tid) * 16), \
          16, 0, 0); }

#define LUNIT(row) (((row) >> 1) * 8 + (((((row) & 1) << 2) + lhi) ^ (((row) >> 1) & 7)))

#define COMPUTE(BUF) { \
    short8v af[4], bf[4]; \
    _Pragma("unroll") \
    for (int tr = 0; tr < 4; tr++){ \
      const int row = wr * 64 + tr * 16 + l15; \
      af[tr] = *(const short8v*)(LDS + (BUF) * 16384 + LUNIT(row) * 16); \
    } \
    _Pragma("unroll") \
    for (int tw = 0; tw < 4; tw++){ \
      const int row = wc * 64 + tw * 16 + l15; \
      bf[tw] = *(const short8v*)(LDS + (BUF) * 16384 + 8192 + LUNIT(row) * 16); \
    } \
    _Pragma("unroll") \
    for (int tr = 0; tr < 4; tr++) \
      _Pragma("unroll") \
      for (int tw = 0; tw < 4; tw++) \
        acc[tr][tw] = __builtin_amdgcn_mfma_f32_16x16x32_bf16( \
            af[tr], bf[tw], acc[tr][tw], 0, 0, 0); }

#define WAIT8  asm volatile("s_waitcnt vmcnt(8)" ::: "memory")
#define WAIT4  asm volatile("s_waitcnt vmcnt(4)" ::: "memory")
#define WAIT0  asm volatile("s_waitcnt vmcnt(0)" ::: "memory")
#define BAR    __builtin_amdgcn_s_barrier()

  STAGE(0, 0);                    // prologue: chunks 0,1 in flight
  STAGE(1, 1);
  #pragma unroll 1
  for (int k = 0; k < 10; k++){   // chunks 3k, 3k+1, 3k+2 in bufs 0,1,2
    const int c = 3 * k;
    STAGE(2, c + 2); WAIT8; BAR; COMPUTE(0); BAR;   // compute chunk c
    STAGE(0, c + 3); WAIT8; BAR; COMPUTE(1); BAR;   // chunk c+1
    STAGE(1, c + 4); WAIT8; BAR; COMPUTE(2); BAR;   // chunk c+2
  }
  WAIT4; BAR; COMPUTE(0); BAR;    // chunk 30 (staged at k=9 step B)
  WAIT0; BAR; COMPUTE(1);         // chunk 31 (staged at k=9 step C)

#undef STAGE
#undef LUNIT
#undef COMPUTE
#undef WAIT8
#undef WAIT4
#undef WAIT0
#undef BAR

  // C/D layout: col = lane&15, row = lhi*4 + j (m89/m91, validated R1-R18).
  // Normal stores: fg lands in L2/L3 so sink reads it at cache latency.
  #pragma unroll
  for (int tr = 0; tr < 4; tr++)
    #pragma unroll
    for (int tw = 0; tw < 4; tw++)
      #pragma unroll
      for (int j = 0; j < 4; j++){
        int m = m0 + wr * 64 + tr * 16 + lhi * 4 + j;
        int n = n0 + wc * 64 + tw * 16 + l15;
        C[(size_t)m * NN + n] = acc[tr][tw][j];
      }
}

// ---- float reduction helpers (validated R1-R18) ----
template<int CTRL>
__device__ __forceinline__ float dpp_add(float x){
  int y = __builtin_amdgcn_mov_dpp(__float_as_int(x), CTRL, 0xF, 0xF, true);
  return x + __int_as_float(y);
}
__device__ __forceinline__ float q16sum(float x){
  x = dpp_add<0x121>(x);   // row_ror:1
  x = dpp_add<0x122>(x);   // row_ror:2
  x = dpp_add<0x124>(x);   // row_ror:4
  x = dpp_add<0x128>(x);   // row_ror:8
  return x;
}
__device__ __forceinline__ float pl16comb(float x){
  unsigned xi = __float_as_uint(x);
  uint2v r = __builtin_amdgcn_permlane16_swap(xi, xi, false, false);
  return __uint_as_float(r[0]) + __uint_as_float(r[1]);
}
__device__ __forceinline__ float pl32comb(float x){
  unsigned xi = __float_as_uint(x);
  uint2v r = __builtin_amdgcn_permlane32_swap(xi, xi, false, false);
  return __uint_as_float(r[0]) + __uint_as_float(r[1]);
}

// ---- Sinkhorn: R11/R18 body (64 VGPR, no spill, ~82% VALUBusy — the
// proven-stable optimum across R12-R15/R19 alternatives). ONE pair per
// wave; quarter q owns rows 9q..9q+8; lane (q,t) holds cols t,t+16,t+32,
// t+48. rowoff/coloff read from ws (written by gather). ----
__global__ __launch_bounds__(256) void sink_kernel(
    const float* __restrict__ fg, const int* __restrict__ il,
    const int* __restrict__ cl, const int* __restrict__ rowoff,
    const int* __restrict__ coloff, float* __restrict__ out){
  const int lane = threadIdx.x & 63;
  const int gw = blockIdx.x * 4 + (threadIdx.x >> 6);   // 16384 waves
  const int i = gw >> 7, c = gw & 127;
  const int q = lane >> 4, t = lane & 15;

  const int ilen = __builtin_amdgcn_readfirstlane(il[i]);
  const int clen = __builtin_amdgcn_readfirstlane(cl[c]);
  const int ro   = __builtin_amdgcn_readfirstlane(rowoff[i]);
  const int co   = __builtin_amdgcn_readfirstlane(coloff[c]);
  const float* base = fg + (size_t)ro * NN + co;        // wave-uniform (saddr)
  const float inv_il = __fdividef(1.0f, (float)ilen);
  const float inv_cl = __fdividef(1.0f, (float)clen);
  const bool v0 = (t      < clen);
  const bool v1 = (t + 16 < clen);
  const bool v2 = (t + 32 < clen);
  const bool v3 = (t + 48 < clen);
  const int r0 = 9 * q;                                 // this quarter's rows
  const int off0 = r0 * NN + t;                         // 32-bit elem offset

  float p0[9], p1[9], p2[9], p3[9];
  float ts = 0.f;
  #pragma unroll
  for (int k = 0; k < 9; k++){
    const bool rv = (r0 + k) < ilen;
    const float a0 = base[off0 + k * NN];
    const float a1 = base[off0 + k * NN + 16];
    const float a2 = base[off0 + k * NN + 32];
    const float a3 = base[off0 + k * NN + 48];
    p0[k] = (rv && v0) ? exp2f(fmaf(a0, L2E20, -L2E20)) : 0.f;
    p1[k] = (rv && v1) ? exp2f(fmaf(a1, L2E20, -L2E20)) : 0.f;
    p2[k] = (rv && v2) ? exp2f(fmaf(a2, L2E20, -L2E20)) : 0.f;
    p3[k] = (rv && v3) ? exp2f(fmaf(a3, L2E20, -L2E20)) : 0.f;
    ts += (p0[k] + p1[k]) + (p2[k] + p3[k]);
  }
  ts = q16sum(ts);
  ts = pl16comb(ts);
  ts = pl32comb(ts);
  const float sc = __fdividef(1.0f, ts + SEPS);         // P /= (sum + EPS)
  #pragma unroll
  for (int k = 0; k < 9; k++){
    p0[k] *= sc; p1[k] *= sc; p2[k] *= sc; p3[k] *= sc;
  }

  for (int it = 0; it < 3; it++){
    #pragma unroll
    for (int k = 0; k < 9; k++){                        // u = rowsum + EPS
      float u = (p0[k] + p1[k]) + (p2[k] + p3[k]);
      u = q16sum(u);
      const float rs = __fdividef(inv_il, u + SEPS);
      p0[k] *= rs; p1[k] *= rs; p2[k] *= rs; p3[k] *= rs;
    }
    float s0 = 0.f, s1 = 0.f, s2 = 0.f, s3 = 0.f;       // colsums (in-lane)
    #pragma unroll
    for (int k = 0; k < 9; k++){
      s0 += p0[k]; s1 += p1[k]; s2 += p2[k]; s3 += p3[k];
    }
    s0 = pl16comb(s0); s0 = pl32comb(s0);
    s1 = pl16comb(s1); s1 = pl32comb(s1);
    s2 = pl16comb(s2); s2 = pl32comb(s2);
    s3 = pl16comb(s3); s3 = pl32comb(s3);
    const float cs0 = __fdividef(inv_cl, s0 + SEPS);
    const float cs1 = __fdividef(inv_cl, s1 + SEPS);
    const float cs2 = __fdividef(inv_cl, s2 + SEPS);
    const float cs3 = __fdividef(inv_cl, s3 + SEPS);
    #pragma unroll
    for (int k = 0; k < 9; k++){
      p0[k] *= cs0; p1[k] *= cs1; p2[k] *= cs2; p3[k] *= cs3;
    }
  }

  float sim = 0.f;
  #pragma unroll
  for (int k = 0; k < 9; k++){                          // reload f (L3-hot)
    sim = fmaf(base[off0 + k * NN],      p0[k], sim);
    sim = fmaf(base[off0 + k * NN + 16], p1[k], sim);
    sim = fmaf(base[off0 + k * NN + 32], p2[k], sim);
    sim = fmaf(base[off0 + k * NN + 48], p3[k], sim);
  }
  sim = q16sum(sim);
  sim = pl16comb(sim);
  sim = pl32comb(sim);
  if (lane == 0) out[i * BT + c] = sim;
}

extern "C" void kernel_launch(void* const* d_in, const int* in_sizes, int n_in,
                              void* d_out, int out_size, void* d_ws, size_t ws_size,
                              hipStream_t stream){
  const float* imgs = (const float*)d_in[0];
  const float* caps = (const float*)d_in[1];
  const int* il = (const int*)d_in[2];
  const int* cl = (const int*)d_in[3];
  float* out = (float*)d_out;

  unsigned short* Ab = (unsigned short*)d_ws;               // [4608][1024] bf16
  unsigned short* Bb = Ab + (size_t)BI * RR * DD;           // [6400][1024] bf16
  float* fg = (float*)(Bb + (size_t)BT * WW * DD);          // [4608][6400] f32
  int* rowoff = (int*)(fg + (size_t)BI * RR * NN);          // [128]
  int* coloff = rowoff + 128;                               // [128]

  gather_cvt_kernel<<<BI * RR + BT * WW, 256, 0, stream>>>(
      imgs, caps, il, cl, Ab, Bb, rowoff, coloff);
  gemm_kernel<<<36 * 50, 256, 0, stream>>>(Ab, Bb, il, cl, fg);
  sink_kernel<<<(BI * BT) / 4, 256, 0, stream>>>(fg, il, cl, rowoff, coloff, out);
}